// Round 3
// baseline (155.569 us; speedup 1.0000x reference)
//
#include <hip/hip_runtime.h>

#define BB 8
#define CC 256
#define HH 64
#define WW 64
#define RED 64
#define HW 4096   // HH*WW
#define AST 72    // xs bf16 row stride ([px][c] layout, 16B-aligned rows)
#define LSF 68    // f32 LDS row stride (res plane in invol_dw)
#define LSH 72    // bf16 LDS row stride (x1 plane in invol_dw; 16B-aligned rows)

typedef __attribute__((ext_vector_type(8))) short s8v;   // 8 bf16 (4 VGPRs)
typedef __attribute__((ext_vector_type(4))) float f4v;   // MFMA accumulator

__device__ __forceinline__ unsigned short f2bf(float f) {  // RNE f32->bf16
    unsigned u = __float_as_uint(f);
    u += 0x7fff + ((u >> 16) & 1);
    return (unsigned short)(u >> 16);
}
__device__ __forceinline__ float b2f(unsigned short u) {   // bf16->f32
    return __uint_as_float(((unsigned)u) << 16);
}

// ---- fused dwconv1 + involution-kernel-generation, MFMA phase B ----
// One block per (row h, batch b): 512 threads = 8 waves.
// Phase A: dwconv1 for a 64-channel chunk -> bf16 LDS tile xs[px][c]; the
// same bf16 values are ALSO streamed to global x1g (bf16 [B][C][H][W]) so
// the second kernel need not recompute dwconv1.
// Phase B: [64px x 64c]x[64c x 64o] via mfma_f32_16x16x32_bf16; wave w =
// (mt = w&3, nh = w>>2) computes px-strip mt*16.. x o-halves nh*32..
// B-frags are built DIRECTLY from w_red (f32, L2-resident) in loadB --
// frag element j is contiguous in c, so each frag = 2 float4 loads + 8
// RNE converts, issued after the MFMA for the NEXT iteration (latency-
// tolerant).  This removes the former build_wtf kernel entirely.
// [R12/R13 variants of this loop both regressed or broke -- this
// two-barrier shape is the verified one; do not re-pipeline.]
__global__ __launch_bounds__(512, 4) void dw_kern(const float* __restrict__ x,
                                                  const float* __restrict__ w_in,
                                                  const float* __restrict__ b_in,
                                                  const float* __restrict__ w_red,
                                                  const float* __restrict__ b_red,
                                                  const float* __restrict__ w_span,  // [9][64]
                                                  const float* __restrict__ b_span,
                                                  float* __restrict__ kern,
                                                  unsigned short* __restrict__ x1g) {
    alignas(16) __shared__ char smem[16640 + 18432];     // 35 KB
    unsigned short* xs = (unsigned short*)smem;          // [64px][AST] bf16 (9.2 KB)
    float* r_lds = (float*)smem;                         // [64o][65] f32, aliases xs (dead)
    float* part  = (float*)(smem + 16640);               // [8og][9][64px]

    const int t  = threadIdx.x;
    const int bx = blockIdx.x;
    const int h  = ((bx & 7) << 3) | (bx >> 3);  // XCD band swizzle
    const int b  = blockIdx.y;
    const int l  = t & 63;                       // lane
    const int wv = t >> 6;                       // wave 0..7
    const int mt = wv & 3, nh = wv >> 2;
    const int m0 = mt << 4;
    // phase-A mapping: 16 col-quads x 32 channel-rows
    const int q  = t & 15;
    const int w0 = q << 2;
    const int cr = t >> 4;                       // 0..31

    float4 pv[2][3]; float plf[2][3], prt[2][3]; // x-row prefetch regs

    auto loadX = [&](int c0) {
        #pragma unroll
        for (int s = 0; s < 2; s++) {
            const int cc = c0 + s * 32 + cr;
            const float* xp = x + ((size_t)(b * CC + cc)) * HW;
            #pragma unroll
            for (int ky = 0; ky < 3; ky++) {
                int hh = h + ky - 1;
                if (hh < 0 || hh >= HH) {        // block-uniform branch
                    pv[s][ky] = make_float4(0.f, 0.f, 0.f, 0.f);
                    plf[s][ky] = 0.f; prt[s][ky] = 0.f;
                    continue;
                }
                const float* row = xp + hh * WW + w0;
                pv[s][ky]  = *(const float4*)row;
                plf[s][ky] = (w0 > 0)      ? row[-1] : 0.f;
                prt[s][ky] = (w0 + 4 < WW) ? row[4]  : 0.f;
            }
        }
    };
    auto computeA = [&](int c0) {                // dwconv from regs -> bf16 xs + x1g
        #pragma unroll
        for (int s = 0; s < 2; s++) {
            const int cl = s * 32 + cr;
            const int cc = c0 + cl;
            const float* wp = w_in + cc * 9;
            const float bb = b_in[cc];
            float4 a4 = make_float4(bb, bb, bb, bb);
            #pragma unroll
            for (int ky = 0; ky < 3; ky++) {
                float4 v = pv[s][ky];
                float lf = plf[s][ky], rt = prt[s][ky];
                float k0 = wp[ky * 3 + 0], k1 = wp[ky * 3 + 1], k2 = wp[ky * 3 + 2];
                a4.x = fmaf(k0, lf,  a4.x); a4.y = fmaf(k0, v.x, a4.y);
                a4.z = fmaf(k0, v.y, a4.z); a4.w = fmaf(k0, v.z, a4.w);
                a4.x = fmaf(k1, v.x, a4.x); a4.y = fmaf(k1, v.y, a4.y);
                a4.z = fmaf(k1, v.z, a4.z); a4.w = fmaf(k1, v.w, a4.w);
                a4.x = fmaf(k2, v.y, a4.x); a4.y = fmaf(k2, v.z, a4.y);
                a4.z = fmaf(k2, v.w, a4.z); a4.w = fmaf(k2, rt,  a4.w);
            }
            ushort4 pk;
            pk.x = f2bf(a4.x); pk.y = f2bf(a4.y);
            pk.z = f2bf(a4.z); pk.w = f2bf(a4.w);
            xs[(w0 + 0) * AST + cl] = pk.x;      // [px][c] for A-frag reads
            xs[(w0 + 1) * AST + cl] = pk.y;
            xs[(w0 + 2) * AST + cl] = pk.z;
            xs[(w0 + 3) * AST + cl] = pk.w;
            // bf16 x1 handoff for kernel 2 (8B store, 128B/16-lane coalesce)
            *(ushort4*)(x1g + ((size_t)(b * CC + cc)) * HW + h * WW + w0) = pk;
        }
    };

    s8v bfr[2][2];                               // B-frags [kb][ntl] for current chunk
    auto loadB = [&](int k) {
        #pragma unroll
        for (int kb = 0; kb < 2; kb++)
            #pragma unroll
            for (int ntl = 0; ntl < 2; ntl++) {
                // B[k][n] = w_red[o=n][c=k]; frag elem j contiguous in c
                const int o   = (((nh << 1) + ntl) << 4) + (l & 15);
                const int c0b = (((k << 1) + kb) << 5) + ((l >> 4) & 3) * 8;
                const float* wr = w_red + o * CC + c0b;
                float4 f0 = *(const float4*)wr;
                float4 f1 = *(const float4*)(wr + 4);
                s8v bv;
                bv[0] = (short)f2bf(f0.x); bv[1] = (short)f2bf(f0.y);
                bv[2] = (short)f2bf(f0.z); bv[3] = (short)f2bf(f0.w);
                bv[4] = (short)f2bf(f1.x); bv[5] = (short)f2bf(f1.y);
                bv[6] = (short)f2bf(f1.z); bv[7] = (short)f2bf(f1.w);
                bfr[kb][ntl] = bv;
            }
    };

    f4v acc[2] = {{0.f, 0.f, 0.f, 0.f}, {0.f, 0.f, 0.f, 0.f}};

    loadX(0); loadB(0);
    for (int k = 0; k < 4; k++) {
        computeA(k << 6);                        // regs -> xs (bf16) + x1g
        if (k < 3) loadX((k + 1) << 6);          // VMEM issue for next chunk
        __syncthreads();
        // phase B: 2 A-frag ds_read_b128 + 4 MFMA per wave
        #pragma unroll
        for (int kb = 0; kb < 2; kb++) {
            const unsigned short* ap =
                xs + (m0 + (l & 15)) * AST + (kb << 5) + ((l >> 4) & 3) * 8;
            s8v av = *(const s8v*)ap;
            #pragma unroll
            for (int ntl = 0; ntl < 2; ntl++)
                acc[ntl] = __builtin_amdgcn_mfma_f32_16x16x32_bf16(
                    av, bfr[kb][ntl], acc[ntl], 0, 0, 0);
        }
        if (k < 3) loadB(k + 1);
        __syncthreads();                         // xs consumed; safe to overwrite
    }

    // C-frags -> r_lds[o][65] (aliases dead xs)
    #pragma unroll
    for (int ntl = 0; ntl < 2; ntl++) {
        int o = ((nh << 1) + ntl) * 16 + (l & 15);
        int pxr = m0 + ((l >> 4) & 3) * 4;       // row = (lane>>4)*4 + i
        #pragma unroll
        for (int i = 0; i < 4; i++)
            r_lds[o * 65 + pxr + i] = acc[ntl][i];
    }
    __syncthreads();

    // epilogue: relu + span contraction + cross-o-group reduction (og = wave)
    const int px = t & 63;
    const int o0 = __builtin_amdgcn_readfirstlane(wv << 3);
    float kk[9];
    #pragma unroll
    for (int j = 0; j < 9; j++) kk[j] = 0.f;
    #pragma unroll
    for (int i = 0; i < 8; i++) {
        float r = fmaxf(r_lds[(o0 + i) * 65 + px] + b_red[o0 + i], 0.f);
        #pragma unroll
        for (int j = 0; j < 9; j++) kk[j] = fmaf(w_span[j * RED + o0 + i], r, kk[j]);
    }
    #pragma unroll
    for (int j = 0; j < 9; j++) part[(wv * 9 + j) * 64 + px] = kk[j];
    __syncthreads();
    if (wv == 0) {
        float* kp = kern + (size_t)b * 9 * HW + h * WW + px;
        #pragma unroll
        for (int j = 0; j < 9; j++) {
            float s = b_span[j];
            #pragma unroll
            for (int g = 0; g < 8; g++) s += part[(g * 9 + j) * 64 + px];
            kp[j * HW] = s;
        }
    }
}

// ---- involution-apply + dwconv2, consuming precomputed bf16 x1 ----
// One block per (c,b) plane: 256 threads x 16 px (4 waves).  Stages the
// bf16 x1 plane (8 KB, written by dw_kern -- dwconv1 is NOT recomputed),
// applies the involution into an f32 LDS plane, then dwconv2 from LDS,
// writes final output.  LDS 26.6 KB -> 6 blocks/CU (was 4 at 34.8 KB).
__global__ __launch_bounds__(256) void invol_dw(const unsigned short* __restrict__ x1g,
                                                const float* __restrict__ kern,
                                                const float* __restrict__ w_out,
                                                const float* __restrict__ b_out,
                                                float* __restrict__ out) {
    __shared__ unsigned short x1s[HH * LSH];     // bf16 x1 plane (9.2 KB)
    __shared__ float res[HH * LSF];              // involution result (17.4 KB)
    const int t  = threadIdx.x;
    const int q  = t & 15;
    const int w0 = q << 2;
    const int r  = t >> 4;                       // 0..15
    const int c = blockIdx.x, b = blockIdx.y;

    // stage x1 plane: 4096 bf16, fully contiguous (16 shorts/thread)
    {
        const unsigned short* xp = x1g + ((size_t)(b * CC + c)) * HW;
        const int hl = t >> 2;                   // 0..63
        const int wl = (t & 3) << 4;             // 0,16,32,48
        *(s8v*)&x1s[hl * LSH + wl]     = *(const s8v*)(xp + hl * WW + wl);
        *(s8v*)&x1s[hl * LSH + wl + 8] = *(const s8v*)(xp + hl * WW + wl + 8);
    }
    __syncthreads();

    // involution apply: out[c,h,w] = sum_k kern[k,h,w] * x1[c, h+dy, w+dx]
    const float* kp = kern + (size_t)b * 9 * HW;
    #pragma unroll
    for (int i = 0; i < 4; i++) {
        int h  = r + (i << 4);
        int hw = h * WW + w0;
        float4 acc = make_float4(0.f, 0.f, 0.f, 0.f);
        #pragma unroll
        for (int ky = 0; ky < 3; ky++) {
            int hh = h + ky - 1;
            if (hh < 0 || hh >= HH) continue;    // zero patch -> zero contribution
            const unsigned short* row = &x1s[hh * LSH + w0];
            float vx = b2f(row[0]), vy = b2f(row[1]);
            float vz = b2f(row[2]), vw = b2f(row[3]);
            float lf = (w0 > 0)      ? b2f(row[-1]) : 0.f;
            float rt = (w0 + 4 < WW) ? b2f(row[4])  : 0.f;
            float4 k0 = *(const float4*)(kp + (ky * 3 + 0) * HW + hw);
            float4 k1 = *(const float4*)(kp + (ky * 3 + 1) * HW + hw);
            float4 k2 = *(const float4*)(kp + (ky * 3 + 2) * HW + hw);
            acc.x = fmaf(k0.x, lf, acc.x); acc.y = fmaf(k0.y, vx, acc.y);
            acc.z = fmaf(k0.z, vy, acc.z); acc.w = fmaf(k0.w, vz, acc.w);
            acc.x = fmaf(k1.x, vx, acc.x); acc.y = fmaf(k1.y, vy, acc.y);
            acc.z = fmaf(k1.z, vz, acc.z); acc.w = fmaf(k1.w, vw, acc.w);
            acc.x = fmaf(k2.x, vy, acc.x); acc.y = fmaf(k2.y, vz, acc.y);
            acc.z = fmaf(k2.z, vw, acc.z); acc.w = fmaf(k2.w, rt, acc.w);
        }
        *(float4*)&res[h * LSF + w0] = acc;
    }
    __syncthreads();

    // dwconv2 from res (f32 LDS), write final output
    const float* wp = w_out + c * 9;             // block-uniform -> s_load
    const float bb = b_out[c];
    float* op = out + ((size_t)(b * CC + c)) * HW;
    #pragma unroll
    for (int i = 0; i < 4; i++) {
        int h = r + (i << 4);
        float4 acc = make_float4(bb, bb, bb, bb);
        #pragma unroll
        for (int ky = 0; ky < 3; ky++) {
            int hh = h + ky - 1;
            if (hh < 0 || hh >= HH) continue;
            const float* row = &res[hh * LSF + w0];
            float4 v = *(const float4*)row;
            float lf = (w0 > 0)      ? row[-1] : 0.f;
            float rt = (w0 + 4 < WW) ? row[4]  : 0.f;
            float k0 = wp[ky * 3 + 0], k1 = wp[ky * 3 + 1], k2 = wp[ky * 3 + 2];
            acc.x = fmaf(k0, lf,  acc.x); acc.y = fmaf(k0, v.x, acc.y);
            acc.z = fmaf(k0, v.y, acc.z); acc.w = fmaf(k0, v.z, acc.w);
            acc.x = fmaf(k1, v.x, acc.x); acc.y = fmaf(k1, v.y, acc.y);
            acc.z = fmaf(k1, v.z, acc.z); acc.w = fmaf(k1, v.w, acc.w);
            acc.x = fmaf(k2, v.y, acc.x); acc.y = fmaf(k2, v.z, acc.y);
            acc.z = fmaf(k2, v.w, acc.z); acc.w = fmaf(k2, rt,  acc.w);
        }
        *(float4*)(op + h * WW + w0) = acc;
    }
}

extern "C" void kernel_launch(void* const* d_in, const int* in_sizes, int n_in,
                              void* d_out, int out_size, void* d_ws, size_t ws_size,
                              hipStream_t stream) {
    const float* x      = (const float*)d_in[0];
    const float* w_in   = (const float*)d_in[1];
    const float* b_in   = (const float*)d_in[2];
    const float* w_red  = (const float*)d_in[3];
    const float* b_red  = (const float*)d_in[4];
    const float* w_span = (const float*)d_in[5];
    const float* b_span = (const float*)d_in[6];
    const float* w_out  = (const float*)d_in[7];
    const float* b_out  = (const float*)d_in[8];
    float* out = (float*)d_out;

    float* kern = (float*)d_ws;                              // 8*9*4096 f32 (1.18 MB)
    unsigned short* x1g = (unsigned short*)(kern + (size_t)BB * 9 * HW); // bf16 x1 (16.8 MB)

    dw_kern<<<dim3(HH, BB), 512, 0, stream>>>(x, w_in, b_in, w_red, b_red,
                                              w_span, b_span, kern, x1g);
    invol_dw<<<dim3(CC, BB), 256, 0, stream>>>(x1g, kern, w_out, b_out, out);
}

// Round 4
// 138.102 us; speedup vs baseline: 1.1265x; 1.1265x over previous
//
#include <hip/hip_runtime.h>

#define BB 8
#define CC 256
#define HH 64
#define WW 64
#define RED 64
#define HW 4096   // HH*WW
#define AST 72    // xs bf16 row stride ([px][c] layout, 16B-aligned rows)
#define LSF 68    // f32 LDS row stride (res plane in invol_dw)
#define LSH 72    // bf16 LDS row stride (x1 plane in invol_dw)

typedef __attribute__((ext_vector_type(8))) short s8v;   // 8 bf16 (4 VGPRs)
typedef __attribute__((ext_vector_type(4))) float f4v;   // MFMA accumulator

__device__ __forceinline__ unsigned short f2bf(float f) {  // RNE f32->bf16
    unsigned u = __float_as_uint(f);
    u += 0x7fff + ((u >> 16) & 1);
    return (unsigned short)(u >> 16);
}
__device__ __forceinline__ float b2f(unsigned short u) {   // bf16->f32
    return __uint_as_float(((unsigned)u) << 16);
}

// ---- build w_red in B-fragment order (bf16) ----
// wtf[e], e = ((kbg*4 + nt)*64 + lane)*8 + j  holds  B[k][n] = w_red[o=n][c=k]
// with n = nt*16 + (lane&15), k = kbg*32 + (lane>>4)*8 + j.  32 KB, L2-resident.
// [Restored from R0 -- the R2 in-loop f32->bf16 loadB put a dependent
// load+convert chain on dw_kern's inter-barrier path; counters showed
// dw_kern latency-bound (VALUBusy 16%, all pipes idle).]
__global__ __launch_bounds__(256) void build_wtf(const float* __restrict__ w_red,
                                                 unsigned short* __restrict__ wtf) {
    int e = blockIdx.x * 256 + threadIdx.x;      // 64 blocks -> 16384
    int j = e & 7, l = (e >> 3) & 63, nt = (e >> 9) & 3, kbg = e >> 11;
    int o = nt * 16 + (l & 15);
    int c = kbg * 32 + ((l >> 4) & 3) * 8 + j;
    wtf[e] = f2bf(w_red[o * CC + c]);
}

// ---- fused dwconv1 + involution-kernel-generation (half-row blocks) ----
// R4 restructure driven by R3 counters (dw_kern 48.8us, MfmaUtil 0.8%,
// VALUBusy 16%, Occupancy 35% -> pure latency-bound at 2 blocks/CU):
//  * 256 threads / 4 waves per block, one block per (half-row, b):
//    grid (128,8)=1024 -> 4 independent blocks/CU (LDS ~20.6KB, waves 16/CU
//    in 4 groups instead of 2) -> barrier stalls interleave across blocks.
//  * w_in/b_in staged once into LDS (wl[c*12+{0..8,9}]) -- removes ~80
//    scattered per-lane VMEM loads per thread from the k-loop.
//  * B-frags from pre-built wtf (single s8v load each).
// MFMA tiling: M=32px, N=64o, K=256c; wave wv -> (mt=wv&1, nh=wv>>1);
// per k-chunk(64c): 2 kb x (1 ds_read_b128 A-frag + 2 MFMA).  Fragment
// layouts byte-identical to the verified R0 kernel.  Two-barrier k-loop
// shape preserved [R12/R13: do not re-pipeline].
__global__ __launch_bounds__(256, 4) void dw_kern(const float* __restrict__ x,
                                                  const float* __restrict__ w_in,
                                                  const float* __restrict__ b_in,
                                                  const unsigned short* __restrict__ wtf,
                                                  const float* __restrict__ b_red,
                                                  const float* __restrict__ w_span,  // [9][64]
                                                  const float* __restrict__ b_span,
                                                  float* __restrict__ kern,
                                                  unsigned short* __restrict__ x1g) {
    alignas(16) __shared__ char smem[8448 + 12288];      // 20.25 KB
    unsigned short* xs = (unsigned short*)smem;          // [32px][AST] bf16 (4.6 KB)
    float* r_lds = (float*)smem;                         // [64o][33] f32, aliases xs (dead)
    float* wl    = (float*)(smem + 8448);                // [256c][12] w_in+b_in staging
    float* part  = (float*)(smem + 8448);                // [8og][9][32px], aliases wl (dead)

    const int t    = threadIdx.x;
    const int bx   = blockIdx.x;
    const int band = bx & 7;                     // XCD band
    const int idx  = bx >> 3;                    // 0..15
    const int h    = band * 8 + (idx >> 1);      // 8 consecutive h per XCD band
    const int wh   = idx & 1;                    // which 32-px half of the row
    const int b    = blockIdx.y;
    const int l  = t & 63;                       // lane
    const int wv = t >> 6;                       // wave 0..3
    const int mt = wv & 1, nh = wv >> 1;
    const int m0 = mt << 4;
    // phase-A mapping: 8 col-quads x 32 channel-rows
    const int q  = t & 7;
    const int pl = q << 2;                       // local px 0..28
    const int wg = (wh << 5) | pl;               // global w 0..60
    const int cr = t >> 3;                       // 0..31

    // stage w_in [256][9] + b_in [256] -> wl[c*12 + {0..8, 9}] (one-time)
    #pragma unroll
    for (int j = 0; j < 9; j++) {
        int i = j * 256 + t;                     // coalesced read of 2304 floats
        wl[(i / 9) * 12 + (i % 9)] = w_in[i];
    }
    wl[t * 12 + 9] = b_in[t];

    float4 pv[2][3]; float plf[2][3], prt[2][3]; // x-row prefetch regs

    auto loadX = [&](int c0) {
        #pragma unroll
        for (int s = 0; s < 2; s++) {
            const int cc = c0 + s * 32 + cr;
            const float* xp = x + ((size_t)(b * CC + cc)) * HW;
            #pragma unroll
            for (int ky = 0; ky < 3; ky++) {
                int hh = h + ky - 1;
                if (hh < 0 || hh >= HH) {        // block-uniform branch
                    pv[s][ky] = make_float4(0.f, 0.f, 0.f, 0.f);
                    plf[s][ky] = 0.f; prt[s][ky] = 0.f;
                    continue;
                }
                const float* row = xp + hh * WW + wg;
                pv[s][ky]  = *(const float4*)row;
                plf[s][ky] = (wg > 0)      ? row[-1] : 0.f;
                prt[s][ky] = (wg + 4 < WW) ? row[4]  : 0.f;
            }
        }
    };
    auto computeA = [&](int c0) {                // dwconv from regs -> bf16 xs + x1g
        #pragma unroll
        for (int s = 0; s < 2; s++) {
            const int cl = s * 32 + cr;
            const int cc = c0 + cl;
            const float* wp = wl + cc * 12;      // weights from LDS (staged once)
            float4 wa = *(const float4*)wp;      // w0..w3
            float4 wb = *(const float4*)(wp + 4);// w4..w7
            float2 wc = *(const float2*)(wp + 8);// w8, bias
            float4 a4 = make_float4(wc.y, wc.y, wc.y, wc.y);
            const float kw[9] = {wa.x, wa.y, wa.z, wa.w, wb.x, wb.y, wb.z, wb.w, wc.x};
            #pragma unroll
            for (int ky = 0; ky < 3; ky++) {
                float4 v = pv[s][ky];
                float lf = plf[s][ky], rt = prt[s][ky];
                float k0 = kw[ky * 3 + 0], k1 = kw[ky * 3 + 1], k2 = kw[ky * 3 + 2];
                a4.x = fmaf(k0, lf,  a4.x); a4.y = fmaf(k0, v.x, a4.y);
                a4.z = fmaf(k0, v.y, a4.z); a4.w = fmaf(k0, v.z, a4.w);
                a4.x = fmaf(k1, v.x, a4.x); a4.y = fmaf(k1, v.y, a4.y);
                a4.z = fmaf(k1, v.z, a4.z); a4.w = fmaf(k1, v.w, a4.w);
                a4.x = fmaf(k2, v.y, a4.x); a4.y = fmaf(k2, v.z, a4.y);
                a4.z = fmaf(k2, v.w, a4.z); a4.w = fmaf(k2, rt,  a4.w);
            }
            ushort4 pk;
            pk.x = f2bf(a4.x); pk.y = f2bf(a4.y);
            pk.z = f2bf(a4.z); pk.w = f2bf(a4.w);
            xs[(pl + 0) * AST + cl] = pk.x;      // [px][c] for A-frag reads
            xs[(pl + 1) * AST + cl] = pk.y;
            xs[(pl + 2) * AST + cl] = pk.z;
            xs[(pl + 3) * AST + cl] = pk.w;
            // bf16 x1 handoff for kernel 2
            *(ushort4*)(x1g + ((size_t)(b * CC + cc)) * HW + h * WW + wg) = pk;
        }
    };

    s8v bfr[2][2];                               // B-frags [kb][ntl] for current chunk
    auto loadB = [&](int k) {
        #pragma unroll
        for (int kb = 0; kb < 2; kb++)
            #pragma unroll
            for (int ntl = 0; ntl < 2; ntl++) {
                int nt = (nh << 1) + ntl;
                int kbg = (k << 1) + kb;
                bfr[kb][ntl] = *(const s8v*)(wtf + (((kbg * 4 + nt) * 64 + l) << 3));
            }
    };

    f4v acc[2] = {{0.f, 0.f, 0.f, 0.f}, {0.f, 0.f, 0.f, 0.f}};

    loadX(0); loadB(0);
    __syncthreads();                             // wl staged before computeA reads it
    for (int k = 0; k < 4; k++) {
        computeA(k << 6);                        // regs -> xs (bf16) + x1g
        if (k < 3) loadX((k + 1) << 6);          // VMEM issue for next chunk
        __syncthreads();
        // phase B: 2 A-frag ds_read_b128 + 4 MFMA per wave
        #pragma unroll
        for (int kb = 0; kb < 2; kb++) {
            const unsigned short* ap =
                xs + (m0 + (l & 15)) * AST + (kb << 5) + ((l >> 4) & 3) * 8;
            s8v av = *(const s8v*)ap;
            #pragma unroll
            for (int ntl = 0; ntl < 2; ntl++)
                acc[ntl] = __builtin_amdgcn_mfma_f32_16x16x32_bf16(
                    av, bfr[kb][ntl], acc[ntl], 0, 0, 0);
        }
        if (k < 3) loadB(k + 1);
        __syncthreads();                         // xs consumed; safe to overwrite
    }

    // C-frags -> r_lds[o][33] (aliases dead xs); D row = px, col = o
    #pragma unroll
    for (int ntl = 0; ntl < 2; ntl++) {
        int o = ((nh << 1) + ntl) * 16 + (l & 15);
        int pxr = m0 + ((l >> 4) & 3) * 4;       // row = (lane>>4)*4 + i
        #pragma unroll
        for (int i = 0; i < 4; i++)
            r_lds[o * 33 + pxr + i] = acc[ntl][i];
    }
    __syncthreads();

    // epilogue: relu + span contraction; og = t>>5 (8 o-groups of 8)
    const int px = t & 31;
    const int og = t >> 5;
    const int o0 = og << 3;
    float kk[9];
    #pragma unroll
    for (int j = 0; j < 9; j++) kk[j] = 0.f;
    #pragma unroll
    for (int i = 0; i < 8; i++) {
        float r = fmaxf(r_lds[(o0 + i) * 33 + px] + b_red[o0 + i], 0.f);
        #pragma unroll
        for (int j = 0; j < 9; j++) kk[j] = fmaf(w_span[j * RED + o0 + i], r, kk[j]);
    }
    __syncthreads();                             // wl dead -> part may overwrite
    #pragma unroll
    for (int j = 0; j < 9; j++) part[(og * 9 + j) * 32 + px] = kk[j];
    __syncthreads();

    // cross-o-group reduction: thread (px, jj) sums 8 partials for kern[jj]
    float* kp = kern + (size_t)b * 9 * HW + h * WW + (wh << 5) + px;
    const int jj = t >> 5;                       // 0..7
    {
        float s = b_span[jj];
        #pragma unroll
        for (int g = 0; g < 8; g++) s += part[(g * 9 + jj) * 32 + px];
        kp[jj * HW] = s;
    }
    if (t < 32) {                                // j = 8 by lanes 0..31
        float s = b_span[8];
        #pragma unroll
        for (int g = 0; g < 8; g++) s += part[(g * 9 + 8) * 32 + px];
        kp[8 * HW] = s;
    }
}

// ---- involution-apply + dwconv2, consuming precomputed bf16 x1 ----
// [Unchanged from R3 -- passed.]  One block per (c,b) plane: 256 threads.
__global__ __launch_bounds__(256) void invol_dw(const unsigned short* __restrict__ x1g,
                                                const float* __restrict__ kern,
                                                const float* __restrict__ w_out,
                                                const float* __restrict__ b_out,
                                                float* __restrict__ out) {
    __shared__ unsigned short x1s[HH * LSH];     // bf16 x1 plane (9.2 KB)
    __shared__ float res[HH * LSF];              // involution result (17.4 KB)
    const int t  = threadIdx.x;
    const int q  = t & 15;
    const int w0 = q << 2;
    const int r  = t >> 4;                       // 0..15
    const int c = blockIdx.x, b = blockIdx.y;

    // stage x1 plane: 4096 bf16, fully contiguous (16 shorts/thread)
    {
        const unsigned short* xp = x1g + ((size_t)(b * CC + c)) * HW;
        const int hl = t >> 2;                   // 0..63
        const int wl2 = (t & 3) << 4;            // 0,16,32,48
        *(s8v*)&x1s[hl * LSH + wl2]     = *(const s8v*)(xp + hl * WW + wl2);
        *(s8v*)&x1s[hl * LSH + wl2 + 8] = *(const s8v*)(xp + hl * WW + wl2 + 8);
    }
    __syncthreads();

    // involution apply: res[h,w] = sum_k kern[k,h,w] * x1[h+dy, w+dx]
    const float* kp = kern + (size_t)b * 9 * HW;
    #pragma unroll
    for (int i = 0; i < 4; i++) {
        int h  = r + (i << 4);
        int hw = h * WW + w0;
        float4 acc = make_float4(0.f, 0.f, 0.f, 0.f);
        #pragma unroll
        for (int ky = 0; ky < 3; ky++) {
            int hh = h + ky - 1;
            if (hh < 0 || hh >= HH) continue;
            const unsigned short* row = &x1s[hh * LSH + w0];
            float vx = b2f(row[0]), vy = b2f(row[1]);
            float vz = b2f(row[2]), vw = b2f(row[3]);
            float lf = (w0 > 0)      ? b2f(row[-1]) : 0.f;
            float rt = (w0 + 4 < WW) ? b2f(row[4])  : 0.f;
            float4 k0 = *(const float4*)(kp + (ky * 3 + 0) * HW + hw);
            float4 k1 = *(const float4*)(kp + (ky * 3 + 1) * HW + hw);
            float4 k2 = *(const float4*)(kp + (ky * 3 + 2) * HW + hw);
            acc.x = fmaf(k0.x, lf, acc.x); acc.y = fmaf(k0.y, vx, acc.y);
            acc.z = fmaf(k0.z, vy, acc.z); acc.w = fmaf(k0.w, vz, acc.w);
            acc.x = fmaf(k1.x, vx, acc.x); acc.y = fmaf(k1.y, vy, acc.y);
            acc.z = fmaf(k1.z, vz, acc.z); acc.w = fmaf(k1.w, vw, acc.w);
            acc.x = fmaf(k2.x, vy, acc.x); acc.y = fmaf(k2.y, vz, acc.y);
            acc.z = fmaf(k2.z, vw, acc.z); acc.w = fmaf(k2.w, rt, acc.w);
        }
        *(float4*)&res[h * LSF + w0] = acc;
    }
    __syncthreads();

    // dwconv2 from res (f32 LDS), write final output
    const float* wp = w_out + c * 9;             // block-uniform -> s_load
    const float bb = b_out[c];
    float* op = out + ((size_t)(b * CC + c)) * HW;
    #pragma unroll
    for (int i = 0; i < 4; i++) {
        int h = r + (i << 4);
        float4 acc = make_float4(bb, bb, bb, bb);
        #pragma unroll
        for (int ky = 0; ky < 3; ky++) {
            int hh = h + ky - 1;
            if (hh < 0 || hh >= HH) continue;
            const float* row = &res[hh * LSF + w0];
            float4 v = *(const float4*)row;
            float lf = (w0 > 0)      ? row[-1] : 0.f;
            float rt = (w0 + 4 < WW) ? row[4]  : 0.f;
            float k0 = wp[ky * 3 + 0], k1 = wp[ky * 3 + 1], k2 = wp[ky * 3 + 2];
            acc.x = fmaf(k0, lf,  acc.x); acc.y = fmaf(k0, v.x, acc.y);
            acc.z = fmaf(k0, v.y, acc.z); acc.w = fmaf(k0, v.z, acc.w);
            acc.x = fmaf(k1, v.x, acc.x); acc.y = fmaf(k1, v.y, acc.y);
            acc.z = fmaf(k1, v.z, acc.z); acc.w = fmaf(k1, v.w, acc.w);
            acc.x = fmaf(k2, v.y, acc.x); acc.y = fmaf(k2, v.z, acc.y);
            acc.z = fmaf(k2, v.w, acc.z); acc.w = fmaf(k2, rt,  acc.w);
        }
        *(float4*)(op + h * WW + w0) = acc;
    }
}

extern "C" void kernel_launch(void* const* d_in, const int* in_sizes, int n_in,
                              void* d_out, int out_size, void* d_ws, size_t ws_size,
                              hipStream_t stream) {
    const float* x      = (const float*)d_in[0];
    const float* w_in   = (const float*)d_in[1];
    const float* b_in   = (const float*)d_in[2];
    const float* w_red  = (const float*)d_in[3];
    const float* b_red  = (const float*)d_in[4];
    const float* w_span = (const float*)d_in[5];
    const float* b_span = (const float*)d_in[6];
    const float* w_out  = (const float*)d_in[7];
    const float* b_out  = (const float*)d_in[8];
    float* out = (float*)d_out;

    float* kern = (float*)d_ws;                              // 1.18 MB
    unsigned short* x1g = (unsigned short*)(kern + (size_t)BB * 9 * HW); // 16.8 MB bf16
    unsigned short* wtf = x1g + (size_t)BB * CC * HW;        // 32 KB bf16

    build_wtf<<<64, 256, 0, stream>>>(w_red, wtf);
    dw_kern<<<dim3(128, BB), 256, 0, stream>>>(x, w_in, b_in, wtf, b_red,
                                               w_span, b_span, kern, x1g);
    invol_dw<<<dim3(CC, BB), 256, 0, stream>>>(x1g, kern, w_out, b_out, out);
}